// Round 3
// baseline (327.666 us; speedup 1.0000x reference)
//
#include <hip/hip_runtime.h>

// OuterProductMean: C[b] = A[b]^T @ B[b] / S ; A,B (32,4096,256) fp32.
// bf16 hi/lo split GEMM, interleaved-packed LDS groups [hi(4k), lo(4k)]:
//   mfma(a, b)        -> hi*hi + lo*lo ; mfma(swap(a), b) -> cross terms
// Now: 32x32x16 MFMA (2382 TF ubench, 4x fewer instrs), 512-thr blocks
// (8 waves, wave tile 64x32), 2 blocks/CU -> 16 waves/CU for latency hiding.
// launch_bounds(512,4): 4 waves/SIMD, 128-reg budget (acc 32 + loads 32).

typedef __attribute__((ext_vector_type(8)))  short  bf16x8;
typedef __attribute__((ext_vector_type(16))) float  f32x16;
typedef __attribute__((ext_vector_type(8)))  ushort u16x8;
typedef __attribute__((ext_vector_type(4)))  float  fvec4;

#define SEQ    4096
#define MD     256
#define KSPLIT 4
#define SCHUNK (SEQ / KSPLIT)   // 1024
#define BK     64
#define NSTEP  (SCHUNK / BK)    // 16

#define FENCE() asm volatile("" ::: "memory")

__device__ __forceinline__ int swz(int m) { return ((m >> 2) ^ (m << 1)) & 15; }

__global__ __launch_bounds__(512, 4) void opm_kernel(const float* __restrict__ A,
                                                     const float* __restrict__ B,
                                                     float* __restrict__ out) {
    const int bid = blockIdx.x;
    const int grp = bid & 127;    // (batch,kc): bid%8 fixes XCD -> siblings share L2
    const int til = bid >> 7;     // sibling tile (mt,nt)
    const int b  = grp >> 2, kc = grp & 3;
    const int mt = til >> 1, nt = til & 1;
    const int tid = threadIdx.x;

    // [m 0..127][16 groups][8 ushort: hi0..3, lo0..3] ; 32 KB each
    __shared__ ushort ldsA[128 * 128];
    __shared__ ushort ldsB[128 * 128];

    // ---- staging addressing: 512 thr stage 64 s-rows x 128 cols of A and B ----
    const int c4 = tid & 31;      // float4 column
    const int sb = tid >> 5;      // 0..15 : 4-row group = one k-group
    const fvec4* gA = (const fvec4*)A + (size_t)b * (SEQ * MD / 4) + mt * 32 + c4;
    const fvec4* gB = (const fvec4*)B + (size_t)b * (SEQ * MD / 4) + nt * 32 + c4;
    const int s0 = kc * SCHUNK;

    // ---- compute addressing: 8 waves 2(m)x4(n), wave tile 64x32 ----
    const int lane = tid & 63;
    const int w   = tid >> 6;
    const int wm  = w >> 2, wn = w & 3;
    const int l31 = lane & 31, lh = lane >> 5;

    const int rowA0 = wm * 64 + l31;
    const int rowA1 = rowA0 + 32;
    const int rowB  = wn * 32 + l31;
    const int sA0 = swz(rowA0), sA1 = swz(rowA1), sB = swz(rowB);

    f32x16 acc0 = {}, acc1 = {};
    fvec4 ra[4], rb[4];

    auto issue = [&](int st) {
        const int srow = s0 + st * BK + sb * 4;
#pragma unroll
        for (int r = 0; r < 4; ++r) {
            ra[r] = gA[(size_t)(srow + r) * (MD / 4)];
            rb[r] = gB[(size_t)(srow + r) * (MD / 4)];
        }
    };

    issue(0);

    for (int st = 0; st < NSTEP; ++st) {
        // convert current tile (frees ra/rb into va/vb)
        u16x8 va[4], vb[4];
#pragma unroll
        for (int j = 0; j < 4; ++j) {
#pragma unroll
            for (int r = 0; r < 4; ++r) {
                const float xa = ra[r][j];
                const uint  ua = __float_as_uint(xa);
                const float la = xa - __uint_as_float(ua & 0xffff0000u);
                va[j][r]     = (ushort)(ua >> 16);
                va[j][4 + r] = (ushort)(__float_as_uint(la) >> 16);
                const float xb = rb[r][j];
                const uint  ub = __float_as_uint(xb);
                const float lb = xb - __uint_as_float(ub & 0xffff0000u);
                vb[j][r]     = (ushort)(ub >> 16);
                vb[j][4 + r] = (ushort)(__float_as_uint(lb) >> 16);
            }
        }
        // prefetch next tile; flies across barriers + MFMA phase
        if (st + 1 < NSTEP) issue(st + 1);
        // transposed swizzled LDS writes (bijective per quarter-wave: conflict-free)
#pragma unroll
        for (int j = 0; j < 4; ++j) {
            const int m   = c4 * 4 + j;
            const int idx = m * 128 + ((sb ^ swz(m)) * 8);
            *(u16x8*)&ldsA[idx] = va[j];
            *(u16x8*)&ldsB[idx] = vb[j];
        }
        FENCE();
        asm volatile("s_waitcnt lgkmcnt(0)" ::: "memory");
        __builtin_amdgcn_s_barrier();   // raw: global prefetch stays in flight
        FENCE();

        // 64 real k: 8 x (8 real k per 32x32x16 via hi/lo packing)
#pragma unroll
        for (int kk = 0; kk < 8; ++kk) {
            const int g = kk * 2 + lh;   // lane half selects k-group
            bf16x8 bf = *(const bf16x8*)&ldsB[rowB  * 128 + ((g ^ sB)  * 8)];
            bf16x8 a0 = *(const bf16x8*)&ldsA[rowA0 * 128 + ((g ^ sA0) * 8)];
            bf16x8 a1 = *(const bf16x8*)&ldsA[rowA1 * 128 + ((g ^ sA1) * 8)];
            acc0 = __builtin_amdgcn_mfma_f32_32x32x16_bf16(a0, bf, acc0, 0, 0, 0);
            acc1 = __builtin_amdgcn_mfma_f32_32x32x16_bf16(a1, bf, acc1, 0, 0, 0);
            const bf16x8 w0 = __builtin_shufflevector(a0, a0, 4, 5, 6, 7, 0, 1, 2, 3);
            const bf16x8 w1 = __builtin_shufflevector(a1, a1, 4, 5, 6, 7, 0, 1, 2, 3);
            acc0 = __builtin_amdgcn_mfma_f32_32x32x16_bf16(w0, bf, acc0, 0, 0, 0);
            acc1 = __builtin_amdgcn_mfma_f32_32x32x16_bf16(w1, bf, acc1, 0, 0, 0);
        }

        FENCE();
        __builtin_amdgcn_s_barrier();   // all reads done before next overwrite
        FENCE();
    }

    // epilogue: scale + atomic accumulate (KSPLIT=4 contributors per output)
    // 32x32 C/D layout: col = lane&31, row = (reg&3) + 8*(reg>>2) + 4*(lane>>5)
    const float inv = 1.0f / (float)SEQ;
    const int   colb = nt * 128 + wn * 32 + l31;
    float* ob = out + (size_t)b * (MD * MD);
#pragma unroll
    for (int tm = 0; tm < 2; ++tm) {
        const int rbase = mt * 128 + wm * 64 + tm * 32 + 4 * lh;
        const f32x16 av = tm ? acc1 : acc0;
#pragma unroll
        for (int reg = 0; reg < 16; ++reg) {
            const int row = rbase + (reg & 3) + 8 * (reg >> 2);
            unsafeAtomicAdd(&ob[row * MD + colb], av[reg] * inv);
        }
    }
}

extern "C" void kernel_launch(void* const* d_in, const int* in_sizes, int n_in,
                              void* d_out, int out_size, void* d_ws, size_t ws_size,
                              hipStream_t stream) {
    const float* A = (const float*)d_in[0];
    const float* B = (const float*)d_in[1];
    float* out     = (float*)d_out;

    hipMemsetAsync(d_out, 0, (size_t)out_size * sizeof(float), stream);

    dim3 grid(512);    // 128 (b,kc) groups x 4 sibling tiles; exactly 2 blocks/CU
    dim3 block(512);   // 8 waves (2x4), wave tile 64x32
    hipLaunchKernelGGL(opm_kernel, grid, block, 0, stream, A, B, out);
}